// Round 3
// baseline (135.953 us; speedup 1.0000x reference)
//
#include <hip/hip_runtime.h>
#include <hip/hip_bf16.h>
#include <math.h>

#define HEADS 4
#define NBKT 196        // coarse buckets = ceil(50176/256); dst>>8
#define CAPB 4608       // per-bucket edge capacity in gbuf (mean 4096, +8 sigma)
#define CAPQ 1792       // per-quarter csr capacity in LDS (mean 1024 + 10 sigma + 64*7 pad)

typedef short bf16x8 __attribute__((ext_vector_type(8)));
typedef float f32x4 __attribute__((ext_vector_type(4)));
typedef unsigned short ushort8 __attribute__((ext_vector_type(8)));

__device__ __forceinline__ float lrelu(float v) { return v >= 0.f ? v : 0.2f * v; }

__device__ __forceinline__ unsigned short f2bf(float f) {
    unsigned u = __float_as_uint(f);
    return (unsigned short)((u + 0x7FFF + ((u >> 16) & 1)) >> 16);
}

__device__ __forceinline__ unsigned pk2bf(float a, float b) {
    __hip_bfloat162 h = __float22bfloat162_rn(make_float2(a, b));
    unsigned u;
    __builtin_memcpy(&u, &h, 4);
    return u;
}

// Zero gcur via a KERNEL, not hipMemsetAsync: small memsets take the SDMA/blit path,
// and each compute->SDMA->compute transition serializes the stream with ~15-20 us of
// engine-switch latency (memset produced no PMC dispatch row -> it was not a kernel).
__global__ void zero_gcur(int* __restrict__ gcur) { gcur[threadIdx.x] = 0; }

// ============ fused kernel: blocks [0,ngemm) = MFMA GEMM; rest = edge binning pass 1 ============
// GEMM path: A streamed straight from global (float4 x2 + inline pk2bf per fragment) — no A-LDS,
// no A sync. B staged in 32 KB LDS, region reused for the bf16 epilogue staging. LDS ~33 KB ->
// 3 blocks/CU at launch_bounds(256,3) vs previous 2 (66 KB tile pair).
__global__ __launch_bounds__(256, 3) void fused_kernel(const float* __restrict__ x,
                                                       const float* __restrict__ W,
                                                       const float* __restrict__ aw,
                                                       const int* __restrict__ ei,
                                                       unsigned short* __restrict__ Wxh,
                                                       float* __restrict__ s_src,
                                                       float* __restrict__ s_dst,
                                                       int* __restrict__ gcur,
                                                       unsigned* __restrict__ gbuf,
                                                       int n, int E, int ngemm) {
    __shared__ __align__(16) char smem[33280];
    const int t = threadIdx.x;

    if ((int)blockIdx.x < ngemm) {
        // ---------------- GEMM path ----------------
        unsigned short* Blds = (unsigned short*)smem;             // 32 KB (B tile, then epilogue staging)
        float* sawm = (float*)(smem + 32768);                     // 256 B
        const int w = t >> 6, l = t & 63;
        const int q = l >> 4, l16 = l & 15;
        const int node0 = blockIdx.x * 128;

        if (t < 64) sawm[t] = aw[t];
        // sentinel init (consumed by pass2_accum next kernel): logits -> w=0, row n -> zeros
        if (blockIdx.x == 0) {
            if (t < 4) s_src[(size_t)n * 4 + t] = -1e30f;
            if (t < 64) ((unsigned*)(Wxh + (size_t)n * 128))[t] = 0u;
        }

#pragma unroll
        for (int i = 0; i < 8; ++i) {
            int c = i * 256 + t;
            int dl = c >> 4, k8 = c & 15;
            const float4* gp = (const float4*)(W + (size_t)dl * 128 + k8 * 8);
            float4 v0 = gp[0], v1 = gp[1];
            uint4 u = make_uint4(pk2bf(v0.x, v0.y), pk2bf(v0.z, v0.w),
                                 pk2bf(v1.x, v1.y), pk2bf(v1.z, v1.w));
            int ch = (((dl >> 4) * 4 + (k8 >> 2)) * 4 + (k8 & 3)) * 16 + (dl & 15);
            *(uint4*)(&Blds[ch * 8]) = u;
        }
        __syncthreads();

        f32x4 acc[2][8];
#pragma unroll
        for (int rt = 0; rt < 2; ++rt)
#pragma unroll
            for (int ct = 0; ct < 8; ++ct) acc[rt][ct] = (f32x4){0.f, 0.f, 0.f, 0.f};

        // A fragment for (rt,kk): lane l holds x[node0 + w*32 + rt*16 + (l&15)][32*kk + 8*(l>>4) ..+7]
        int g0 = node0 + w * 32 + l16;
        int g1 = g0 + 16;
        if (g0 >= n) g0 = n - 1;
        if (g1 >= n) g1 = n - 1;
        const float* xr0 = x + (size_t)g0 * 128 + q * 8;
        const float* xr1 = x + (size_t)g1 * 128 + q * 8;

#pragma unroll
        for (int kk = 0; kk < 4; ++kk) {
            const float4* pa0 = (const float4*)(xr0 + kk * 32);
            const float4* pa1 = (const float4*)(xr1 + kk * 32);
            float4 v0 = pa0[0], v1 = pa0[1];
            float4 v2 = pa1[0], v3 = pa1[1];
            uint4 ua0 = make_uint4(pk2bf(v0.x, v0.y), pk2bf(v0.z, v0.w),
                                   pk2bf(v1.x, v1.y), pk2bf(v1.z, v1.w));
            uint4 ua1 = make_uint4(pk2bf(v2.x, v2.y), pk2bf(v2.z, v2.w),
                                   pk2bf(v3.x, v3.y), pk2bf(v3.z, v3.w));
            bf16x8 a0, a1;
            __builtin_memcpy(&a0, &ua0, 16);
            __builtin_memcpy(&a1, &ua1, 16);
#pragma unroll
            for (int ct = 0; ct < 8; ++ct) {
                bf16x8 b = *(const bf16x8*)(&Blds[((ct * 4 + kk) * 64 + l) * 8]);
                acc[0][ct] = __builtin_amdgcn_mfma_f32_16x16x32_bf16(a0, b, acc[0][ct], 0, 0, 0);
                acc[1][ct] = __builtin_amdgcn_mfma_f32_16x16x32_bf16(a1, b, acc[1][ct], 0, 0, 0);
            }
        }

        __syncthreads();   // B tile dead; reuse LDS for epilogue staging
        // C/D layout: col = lane&15, row = (lane>>4)*4 + reg  [verified m89/m91]
#pragma unroll
        for (int rt = 0; rt < 2; ++rt) {
            int nl = w * 32 + rt * 16 + q * 4;
#pragma unroll
            for (int ct = 0; ct < 8; ++ct) {
                int dim = ct * 16 + l16;
                Blds[(nl + 0) * 128 + dim] = f2bf(acc[rt][ct][0]);
                Blds[(nl + 1) * 128 + dim] = f2bf(acc[rt][ct][1]);
                Blds[(nl + 2) * 128 + dim] = f2bf(acc[rt][ct][2]);
                Blds[(nl + 3) * 128 + dim] = f2bf(acc[rt][ct][3]);
            }
        }
        __syncthreads();

#pragma unroll
        for (int i = 0; i < 8; ++i) {
            int c = i * 256 + t;
            int nl = c >> 4, d8 = c & 15;
            int gn = node0 + nl;
            ushort8 u = *(const ushort8*)(&Blds[nl * 128 + d8 * 8]);
            if (gn < n) *(ushort8*)(Wxh + (size_t)gn * 128 + d8 * 8) = u;
            float sp = 0.f, dp = 0.f;
            int ab = (d8 & 3) * 8;
#pragma unroll
            for (int j = 0; j < 8; ++j) {
                float v = __uint_as_float(((unsigned)(unsigned short)u[j]) << 16);
                sp += v * sawm[ab + j];
                dp += v * sawm[32 + ab + j];
            }
            sp += __shfl_xor(sp, 1, 64); dp += __shfl_xor(dp, 1, 64);
            sp += __shfl_xor(sp, 2, 64); dp += __shfl_xor(dp, 2, 64);
            if ((l & 3) == 0 && gn < n) {
                int h = (l & 15) >> 2;
                s_src[(size_t)gn * 4 + h] = sp;
                s_dst[(size_t)gn * 4 + h] = dp;
            }
        }
    } else {
        // ---------------- binning pass 1 ----------------
        int* hist = (int*)smem;
        int* scanws = (int*)(smem + 1024);
        int* lbase = (int*)(smem + 2048);
        int* lcur = (int*)(smem + 3072);
        int* gb = (int*)(smem + 4096);
        unsigned* sorted = (unsigned*)(smem + 5120);      // 16 KB
        unsigned char* bkt = (unsigned char*)(smem + 21504); // 4 KB -> ends 25600

        const int blk = blockIdx.x - ngemm;
        const int b0 = blk * 4096;
        const int total = min(4096, E - b0);

        hist[t] = 0;
        __syncthreads();

        unsigned pk[16];
#pragma unroll
        for (int i = 0; i < 16; ++i) {
            int idx = i * 256 + t;
            if (idx < total) {
                int e = b0 + idx;
                unsigned s = (unsigned)ei[e], d = (unsigned)ei[E + e];
                pk[i] = s | (d << 16);
                atomicAdd(&hist[d >> 8], 1);
            }
        }
        __syncthreads();
        int v = hist[t];
        scanws[t] = v;
        __syncthreads();
        for (int off = 1; off < 256; off <<= 1) {
            int y = (t >= off) ? scanws[t - off] : 0;
            __syncthreads();
            scanws[t] += y;
            __syncthreads();
        }
        int ex = scanws[t] - v;
        lbase[t] = ex;
        lcur[t] = ex;
        if (t < NBKT) gb[t] = (v > 0) ? atomicAdd(&gcur[t], v) : 0;
        __syncthreads();
#pragma unroll
        for (int i = 0; i < 16; ++i) {
            int idx = i * 256 + t;
            if (idx < total) {
                int b = pk[i] >> 24;
                int qpos = atomicAdd(&lcur[b], 1);
                sorted[qpos] = pk[i];
                bkt[qpos] = (unsigned char)b;
            }
        }
        __syncthreads();
#pragma unroll
        for (int i = 0; i < 16; ++i) {
            int s = i * 256 + t;
            if (s < total) {
                int b = bkt[s];
                int pos = gb[b] + (s - lbase[b]);
                if (pos < CAPB) gbuf[(size_t)b * CAPB + pos] = sorted[s];
            }
        }
    }
}

// ============ merged pass2 + accumulate: one block per quarter-bucket (64 nodes) ============
// 512 threads (8 waves): 784 blocks x 8 = 6272 waves -> ~24.5 waves/CU in a single balanced
// round (was 12 waves/CU at 256 threads; measured OccupancyPercent 23%, latency-bound).
__global__ __launch_bounds__(512) void pass2_accum(const int* __restrict__ gcur,
                                                   const unsigned* __restrict__ gbuf,
                                                   const float* __restrict__ s_src,
                                                   const float* __restrict__ s_dst,
                                                   const unsigned short* __restrict__ Wxh,
                                                   float* __restrict__ out, int n) {
    __shared__ int hist[64], basew[64], cur[64];
    __shared__ __align__(16) unsigned short csrl[CAPQ];
    const int t = threadIdx.x;
    const int bucket = blockIdx.x >> 2;
    const unsigned quarter = blockIdx.x & 3;
    int cnt = gcur[bucket];
    if (cnt > CAPB) cnt = CAPB;
    const unsigned* gp = gbuf + (size_t)bucket * CAPB;

    if (t < 64) hist[t] = 0;
    __syncthreads();

    // (1) filter + histogram. 9*512 = 4608 = CAPB. Sentinel 0xFFFFFFFF impossible (dst < 50000).
    unsigned pk[9];
#pragma unroll
    for (int i = 0; i < 9; ++i) {
        int idx = i * 512 + t;
        pk[i] = 0xFFFFFFFFu;
        if (idx < cnt) {
            unsigned u = gp[idx];
            if (((u >> 22) & 3u) == quarter) {
                pk[i] = u;
                atomicAdd(&hist[(u >> 16) & 63], 1);
            }
        }
    }
    __syncthreads();

    // (2) wave-0 scan of padded degrees; write pad sentinels; hist <- padded degree
    if (t < 64) {
        int v = hist[t];
        int vp = (v + 7) & ~7;
        int sc = vp;
#pragma unroll
        for (int off = 1; off < 64; off <<= 1) {
            int y = __shfl_up(sc, off, 64);
            if (t >= off) sc += y;
        }
        int base = sc - vp;             // exclusive scan
        basew[t] = base;
        cur[t] = base;
        for (int j = v; j < vp; ++j) {
            int pos = base + j;
            if (pos < CAPQ) csrl[pos] = (unsigned short)n;   // sentinel src
        }
        hist[t] = vp;
    }
    __syncthreads();

    // (3) scatter into LDS csr
#pragma unroll
    for (int i = 0; i < 9; ++i) {
        unsigned u = pk[i];
        if (u != 0xFFFFFFFFu) {
            int bin = (u >> 16) & 63;
            int pos = atomicAdd(&cur[bin], 1);
            if (pos < CAPQ) csrl[pos] = (unsigned short)(u & 0xFFFF);
        }
    }
    __syncthreads();

    // (4) accumulate. 16 lanes x 16B bf16 row; 4 lane-groups take adjacent edge pairs.
    const int wid = t >> 6, lane = t & 63;
    const int l = lane & 15, grp = lane >> 4, h = l >> 2;
    const unsigned ONE2 = 0x3F803F80u;      // bf16 (1.0, 1.0)

    for (int ln = wid; ln < 64; ln += 8) {
        int node = bucket * 256 + (int)quarter * 64 + ln;
        if (node >= n) break;               // wave-uniform
        int start = basew[ln];
        int npairs = hist[ln] >> 1;         // multiple of 4
        float sdn = s_dst[(size_t)node * 4 + h];

        float acc[8] = {0.f, 0.f, 0.f, 0.f, 0.f, 0.f, 0.f, 0.f};
        float dsum = 0.f;
        int p = grp;
        for (; p + 4 < npairs; p += 8) {
            unsigned c0 = *(const unsigned*)(&csrl[start + 2 * p]);
            unsigned c1 = *(const unsigned*)(&csrl[start + 2 * (p + 4)]);
            int sa0 = c0 & 0xFFFF, sa1 = c0 >> 16;
            int sb0 = c1 & 0xFFFF, sb1 = c1 >> 16;
            uint4 Ua0 = *(const uint4*)(Wxh + ((size_t)sa0 << 7) + l * 8);
            uint4 Ua1 = *(const uint4*)(Wxh + ((size_t)sa1 << 7) + l * 8);
            uint4 Ub0 = *(const uint4*)(Wxh + ((size_t)sb0 << 7) + l * 8);
            uint4 Ub1 = *(const uint4*)(Wxh + ((size_t)sb1 << 7) + l * 8);
            float wa0 = __expf(lrelu(s_src[sa0 * 4 + h] + sdn));
            float wa1 = __expf(lrelu(s_src[sa1 * 4 + h] + sdn));
            float wb0 = __expf(lrelu(s_src[sb0 * 4 + h] + sdn));
            float wb1 = __expf(lrelu(s_src[sb1 * 4 + h] + sdn));
            unsigned wpa = pk2bf(wa0, wa1);
            unsigned wpb = pk2bf(wb0, wb1);
            asm("v_dot2_f32_bf16 %0, %1, %2, %0" : "+v"(dsum) : "v"(wpa), "v"(ONE2));
            asm("v_dot2_f32_bf16 %0, %1, %2, %0" : "+v"(dsum) : "v"(wpb), "v"(ONE2));
            unsigned a0[4] = {Ua0.x, Ua0.y, Ua0.z, Ua0.w};
            unsigned a1[4] = {Ua1.x, Ua1.y, Ua1.z, Ua1.w};
            unsigned b0[4] = {Ub0.x, Ub0.y, Ub0.z, Ub0.w};
            unsigned b1[4] = {Ub1.x, Ub1.y, Ub1.z, Ub1.w};
#pragma unroll
            for (int j = 0; j < 4; ++j) {
                unsigned lo_a = __builtin_amdgcn_perm(a0[j], a1[j], 0x01000504u);
                unsigned hi_a = __builtin_amdgcn_perm(a0[j], a1[j], 0x03020706u);
                unsigned lo_b = __builtin_amdgcn_perm(b0[j], b1[j], 0x01000504u);
                unsigned hi_b = __builtin_amdgcn_perm(b0[j], b1[j], 0x03020706u);
                asm("v_dot2_f32_bf16 %0, %1, %2, %0" : "+v"(acc[2 * j]) : "v"(wpa), "v"(lo_a));
                asm("v_dot2_f32_bf16 %0, %1, %2, %0" : "+v"(acc[2 * j + 1]) : "v"(wpa), "v"(hi_a));
                asm("v_dot2_f32_bf16 %0, %1, %2, %0" : "+v"(acc[2 * j]) : "v"(wpb), "v"(lo_b));
                asm("v_dot2_f32_bf16 %0, %1, %2, %0" : "+v"(acc[2 * j + 1]) : "v"(wpb), "v"(hi_b));
            }
        }
        if (p < npairs) {                   // tail: 4 pairs, wave-uniform condition
            unsigned c0 = *(const unsigned*)(&csrl[start + 2 * p]);
            int sa0 = c0 & 0xFFFF, sa1 = c0 >> 16;
            uint4 Ua0 = *(const uint4*)(Wxh + ((size_t)sa0 << 7) + l * 8);
            uint4 Ua1 = *(const uint4*)(Wxh + ((size_t)sa1 << 7) + l * 8);
            float wa0 = __expf(lrelu(s_src[sa0 * 4 + h] + sdn));
            float wa1 = __expf(lrelu(s_src[sa1 * 4 + h] + sdn));
            unsigned wpa = pk2bf(wa0, wa1);
            asm("v_dot2_f32_bf16 %0, %1, %2, %0" : "+v"(dsum) : "v"(wpa), "v"(ONE2));
            unsigned a0[4] = {Ua0.x, Ua0.y, Ua0.z, Ua0.w};
            unsigned a1[4] = {Ua1.x, Ua1.y, Ua1.z, Ua1.w};
#pragma unroll
            for (int j = 0; j < 4; ++j) {
                unsigned lo_a = __builtin_amdgcn_perm(a0[j], a1[j], 0x01000504u);
                unsigned hi_a = __builtin_amdgcn_perm(a0[j], a1[j], 0x03020706u);
                asm("v_dot2_f32_bf16 %0, %1, %2, %0" : "+v"(acc[2 * j]) : "v"(wpa), "v"(lo_a));
                asm("v_dot2_f32_bf16 %0, %1, %2, %0" : "+v"(acc[2 * j + 1]) : "v"(wpa), "v"(hi_a));
            }
        }
#pragma unroll
        for (int m = 16; m <= 32; m <<= 1) {
#pragma unroll
            for (int j = 0; j < 8; ++j) acc[j] += __shfl_xor(acc[j], m, 64);
            dsum += __shfl_xor(dsum, m, 64);
        }
        if (grp == 0) {
            float inv = 1.f / (dsum + 1e-8f);
            float o[8];
#pragma unroll
            for (int j = 0; j < 8; ++j) {
                float v = acc[j] * inv;
                o[j] = v > 0.f ? v : (__expf(v) - 1.f);
            }
            float4* dp = (float4*)(out + (size_t)node * 128 + l * 8);
            dp[0] = make_float4(o[0], o[1], o[2], o[3]);
            dp[1] = make_float4(o[4], o[5], o[6], o[7]);
        }
    }
}

extern "C" void kernel_launch(void* const* d_in, const int* in_sizes, int n_in,
                              void* d_out, int out_size, void* d_ws, size_t ws_size,
                              hipStream_t stream) {
    const float* x = (const float*)d_in[0];
    const int* ei = (const int*)d_in[1];
    const float* W = (const float*)d_in[2];
    const float* aw = (const float*)d_in[3];
    float* out = (float*)d_out;
    const int n = in_sizes[0] / 128;      // 50000
    const int E = in_sizes[1] / 2;        // 800000

    char* ws = (char*)d_ws;
    size_t off = 0;
    unsigned short* Wxh = (unsigned short*)(ws + off); off += (size_t)(n + 8) * 128 * 2;  // +sentinel row
    float* s_src = (float*)(ws + off);     off += (size_t)(n + 1) * HEADS * 4;            // +sentinel slot
    float* s_dst = (float*)(ws + off);     off += (size_t)n * HEADS * 4;
    int* gcur = (int*)(ws + off);          off += 1024;
    unsigned* gbuf = (unsigned*)(ws + off); off += (size_t)NBKT * CAPB * 4;               // 3.6 MB

    const int ngemm = (n + 127) / 128;                 // 391
    const int npass1 = (E + 4095) / 4096;              // 196

    zero_gcur<<<1, 256, 0, stream>>>(gcur);            // kernel, NOT hipMemsetAsync (SDMA engine switch)
    fused_kernel<<<ngemm + npass1, 256, 0, stream>>>(x, W, aw, ei, Wxh, s_src, s_dst,
                                                     gcur, gbuf, n, E, ngemm);
    pass2_accum<<<NBKT * 4, 512, 0, stream>>>(gcur, gbuf, s_src, s_dst, Wxh, out, n);
}

// Round 4
// 134.429 us; speedup vs baseline: 1.0113x; 1.0113x over previous
//
#include <hip/hip_runtime.h>
#include <hip/hip_bf16.h>
#include <math.h>

#define HEADS 4
#define NBKT 196        // coarse buckets = ceil(50176/256); dst>>8
#define CAPB 4608       // per-bucket edge capacity in gbuf (mean 4096, +8 sigma)
#define CAPQ 1792       // per-quarter csr capacity in LDS (mean 1024 + 10 sigma + 64*7 pad)

typedef short bf16x8 __attribute__((ext_vector_type(8)));
typedef float f32x4 __attribute__((ext_vector_type(4)));
typedef unsigned short ushort8 __attribute__((ext_vector_type(8)));

__device__ __forceinline__ float lrelu(float v) { return v >= 0.f ? v : 0.2f * v; }

__device__ __forceinline__ unsigned short f2bf(float f) {
    unsigned u = __float_as_uint(f);
    return (unsigned short)((u + 0x7FFF + ((u >> 16) & 1)) >> 16);
}

__device__ __forceinline__ unsigned pk2bf(float a, float b) {
    __hip_bfloat162 h = __float22bfloat162_rn(make_float2(a, b));
    unsigned u;
    __builtin_memcpy(&u, &h, 4);
    return u;
}

__global__ void zero_gcur(int* __restrict__ gcur) { gcur[threadIdx.x] = 0; }

// ============ fused kernel: blocks [0,ngemm) = MFMA GEMM; rest = edge binning pass 1 ============
__global__ __launch_bounds__(256, 3) void fused_kernel(const float* __restrict__ x,
                                                       const float* __restrict__ W,
                                                       const float* __restrict__ aw,
                                                       const int* __restrict__ ei,
                                                       unsigned short* __restrict__ Wxh,
                                                       float* __restrict__ s_src,
                                                       float* __restrict__ s_dst,
                                                       int* __restrict__ gcur,
                                                       unsigned* __restrict__ gbuf,
                                                       int n, int E, int ngemm) {
    __shared__ __align__(16) char smem[33280];
    const int t = threadIdx.x;

    if ((int)blockIdx.x < ngemm) {
        // ---------------- GEMM path ----------------
        unsigned short* Blds = (unsigned short*)smem;             // 32 KB (B tile, then epilogue staging)
        float* sawm = (float*)(smem + 32768);                     // 256 B
        const int w = t >> 6, l = t & 63;
        const int q = l >> 4, l16 = l & 15;
        const int node0 = blockIdx.x * 128;

        if (t < 64) sawm[t] = aw[t];
        // sentinel init (consumed by pass2_accum next kernel): logits -> w=0, row n -> zeros
        if (blockIdx.x == 0) {
            if (t < 4) s_src[(size_t)n * 4 + t] = -1e30f;
            if (t < 64) ((unsigned*)(Wxh + (size_t)n * 128))[t] = 0u;
        }

#pragma unroll
        for (int i = 0; i < 8; ++i) {
            int c = i * 256 + t;
            int dl = c >> 4, k8 = c & 15;
            const float4* gp = (const float4*)(W + (size_t)dl * 128 + k8 * 8);
            float4 v0 = gp[0], v1 = gp[1];
            uint4 u = make_uint4(pk2bf(v0.x, v0.y), pk2bf(v0.z, v0.w),
                                 pk2bf(v1.x, v1.y), pk2bf(v1.z, v1.w));
            int ch = (((dl >> 4) * 4 + (k8 >> 2)) * 4 + (k8 & 3)) * 16 + (dl & 15);
            *(uint4*)(&Blds[ch * 8]) = u;
        }
        __syncthreads();

        f32x4 acc[2][8];
#pragma unroll
        for (int rt = 0; rt < 2; ++rt)
#pragma unroll
            for (int ct = 0; ct < 8; ++ct) acc[rt][ct] = (f32x4){0.f, 0.f, 0.f, 0.f};

        // A fragment for (rt,kk): lane l holds x[node0 + w*32 + rt*16 + (l&15)][32*kk + 8*(l>>4) ..+7]
        int g0 = node0 + w * 32 + l16;
        int g1 = g0 + 16;
        if (g0 >= n) g0 = n - 1;
        if (g1 >= n) g1 = n - 1;
        const float* xr0 = x + (size_t)g0 * 128 + q * 8;
        const float* xr1 = x + (size_t)g1 * 128 + q * 8;

#pragma unroll
        for (int kk = 0; kk < 4; ++kk) {
            const float4* pa0 = (const float4*)(xr0 + kk * 32);
            const float4* pa1 = (const float4*)(xr1 + kk * 32);
            float4 v0 = pa0[0], v1 = pa0[1];
            float4 v2 = pa1[0], v3 = pa1[1];
            uint4 ua0 = make_uint4(pk2bf(v0.x, v0.y), pk2bf(v0.z, v0.w),
                                   pk2bf(v1.x, v1.y), pk2bf(v1.z, v1.w));
            uint4 ua1 = make_uint4(pk2bf(v2.x, v2.y), pk2bf(v2.z, v2.w),
                                   pk2bf(v3.x, v3.y), pk2bf(v3.z, v3.w));
            bf16x8 a0, a1;
            __builtin_memcpy(&a0, &ua0, 16);
            __builtin_memcpy(&a1, &ua1, 16);
#pragma unroll
            for (int ct = 0; ct < 8; ++ct) {
                bf16x8 b = *(const bf16x8*)(&Blds[((ct * 4 + kk) * 64 + l) * 8]);
                acc[0][ct] = __builtin_amdgcn_mfma_f32_16x16x32_bf16(a0, b, acc[0][ct], 0, 0, 0);
                acc[1][ct] = __builtin_amdgcn_mfma_f32_16x16x32_bf16(a1, b, acc[1][ct], 0, 0, 0);
            }
        }

        __syncthreads();   // B tile dead; reuse LDS for epilogue staging
        // C/D layout: col = lane&15, row = (lane>>4)*4 + reg  [verified m89/m91]
#pragma unroll
        for (int rt = 0; rt < 2; ++rt) {
            int nl = w * 32 + rt * 16 + q * 4;
#pragma unroll
            for (int ct = 0; ct < 8; ++ct) {
                int dim = ct * 16 + l16;
                Blds[(nl + 0) * 128 + dim] = f2bf(acc[rt][ct][0]);
                Blds[(nl + 1) * 128 + dim] = f2bf(acc[rt][ct][1]);
                Blds[(nl + 2) * 128 + dim] = f2bf(acc[rt][ct][2]);
                Blds[(nl + 3) * 128 + dim] = f2bf(acc[rt][ct][3]);
            }
        }
        __syncthreads();

#pragma unroll
        for (int i = 0; i < 8; ++i) {
            int c = i * 256 + t;
            int nl = c >> 4, d8 = c & 15;
            int gn = node0 + nl;
            ushort8 u = *(const ushort8*)(&Blds[nl * 128 + d8 * 8]);
            if (gn < n) *(ushort8*)(Wxh + (size_t)gn * 128 + d8 * 8) = u;
            float sp = 0.f, dp = 0.f;
            int ab = (d8 & 3) * 8;
#pragma unroll
            for (int j = 0; j < 8; ++j) {
                float v = __uint_as_float(((unsigned)(unsigned short)u[j]) << 16);
                sp += v * sawm[ab + j];
                dp += v * sawm[32 + ab + j];
            }
            sp += __shfl_xor(sp, 1, 64); dp += __shfl_xor(dp, 1, 64);
            sp += __shfl_xor(sp, 2, 64); dp += __shfl_xor(dp, 2, 64);
            if ((l & 3) == 0 && gn < n) {
                int h = (l & 15) >> 2;
                s_src[(size_t)gn * 4 + h] = sp;
                s_dst[(size_t)gn * 4 + h] = dp;
            }
        }
    } else {
        // ---------------- binning pass 1 ----------------
        int* hist = (int*)smem;
        int* scanws = (int*)(smem + 1024);
        int* lbase = (int*)(smem + 2048);
        int* lcur = (int*)(smem + 3072);
        int* gb = (int*)(smem + 4096);
        unsigned* sorted = (unsigned*)(smem + 5120);      // 16 KB
        unsigned char* bkt = (unsigned char*)(smem + 21504); // 4 KB -> ends 25600

        const int blk = blockIdx.x - ngemm;
        const int b0 = blk * 4096;
        const int total = min(4096, E - b0);

        hist[t] = 0;
        __syncthreads();

        unsigned pk[16];
#pragma unroll
        for (int i = 0; i < 16; ++i) {
            int idx = i * 256 + t;
            if (idx < total) {
                int e = b0 + idx;
                unsigned s = (unsigned)ei[e], d = (unsigned)ei[E + e];
                pk[i] = s | (d << 16);
                atomicAdd(&hist[d >> 8], 1);
            }
        }
        __syncthreads();
        int v = hist[t];
        scanws[t] = v;
        __syncthreads();
        for (int off = 1; off < 256; off <<= 1) {
            int y = (t >= off) ? scanws[t - off] : 0;
            __syncthreads();
            scanws[t] += y;
            __syncthreads();
        }
        int ex = scanws[t] - v;
        lbase[t] = ex;
        lcur[t] = ex;
        if (t < NBKT) gb[t] = (v > 0) ? atomicAdd(&gcur[t], v) : 0;
        __syncthreads();
#pragma unroll
        for (int i = 0; i < 16; ++i) {
            int idx = i * 256 + t;
            if (idx < total) {
                int b = pk[i] >> 24;
                int qpos = atomicAdd(&lcur[b], 1);
                sorted[qpos] = pk[i];
                bkt[qpos] = (unsigned char)b;
            }
        }
        __syncthreads();
#pragma unroll
        for (int i = 0; i < 16; ++i) {
            int s = i * 256 + t;
            if (s < total) {
                int b = bkt[s];
                int pos = gb[b] + (s - lbase[b]);
                if (pos < CAPB) gbuf[(size_t)b * CAPB + pos] = sorted[s];
            }
        }
    }
}

// ============ merged pass2 + accumulate: one block per quarter-bucket (64 nodes) ============
// 1024 threads (16 waves): 784 blocks, 2 blocks/CU co-resident = 32 waves/CU — the hardware
// occupancy cap (R1 measured 23% occ / 38.6% VALUBusy at 4 waves; R2's 8 waves gained ~6 us;
// this round discriminates latency-bound (H2: big gain) vs LLC-BW-bound (H1: null).
__global__ __launch_bounds__(1024) void pass2_accum(const int* __restrict__ gcur,
                                                    const unsigned* __restrict__ gbuf,
                                                    const float* __restrict__ s_src,
                                                    const float* __restrict__ s_dst,
                                                    const unsigned short* __restrict__ Wxh,
                                                    float* __restrict__ out, int n) {
    __shared__ int hist[64], basew[64], cur[64];
    __shared__ __align__(16) unsigned short csrl[CAPQ];
    const int t = threadIdx.x;
    const int bucket = blockIdx.x >> 2;
    const unsigned quarter = blockIdx.x & 3;
    int cnt = gcur[bucket];
    if (cnt > CAPB) cnt = CAPB;
    const unsigned* gp = gbuf + (size_t)bucket * CAPB;

    if (t < 64) hist[t] = 0;
    __syncthreads();

    // (1) filter + histogram. 5*1024 = 5120 >= CAPB. Sentinel 0xFFFFFFFF impossible (dst < 50000).
    unsigned pk[5];
#pragma unroll
    for (int i = 0; i < 5; ++i) {
        int idx = i * 1024 + t;
        pk[i] = 0xFFFFFFFFu;
        if (idx < cnt) {
            unsigned u = gp[idx];
            if (((u >> 22) & 3u) == quarter) {
                pk[i] = u;
                atomicAdd(&hist[(u >> 16) & 63], 1);
            }
        }
    }
    __syncthreads();

    // (2) wave-0 scan of padded degrees; write pad sentinels; hist <- padded degree
    if (t < 64) {
        int v = hist[t];
        int vp = (v + 7) & ~7;
        int sc = vp;
#pragma unroll
        for (int off = 1; off < 64; off <<= 1) {
            int y = __shfl_up(sc, off, 64);
            if (t >= off) sc += y;
        }
        int base = sc - vp;             // exclusive scan
        basew[t] = base;
        cur[t] = base;
        for (int j = v; j < vp; ++j) {
            int pos = base + j;
            if (pos < CAPQ) csrl[pos] = (unsigned short)n;   // sentinel src
        }
        hist[t] = vp;
    }
    __syncthreads();

    // (3) scatter into LDS csr
#pragma unroll
    for (int i = 0; i < 5; ++i) {
        unsigned u = pk[i];
        if (u != 0xFFFFFFFFu) {
            int bin = (u >> 16) & 63;
            int pos = atomicAdd(&cur[bin], 1);
            if (pos < CAPQ) csrl[pos] = (unsigned short)(u & 0xFFFF);
        }
    }
    __syncthreads();

    // (4) accumulate. 16 lanes x 16B bf16 row; 4 lane-groups take adjacent edge pairs.
    const int wid = t >> 6, lane = t & 63;
    const int l = lane & 15, grp = lane >> 4, h = l >> 2;
    const unsigned ONE2 = 0x3F803F80u;      // bf16 (1.0, 1.0)

    for (int ln = wid; ln < 64; ln += 16) {
        int node = bucket * 256 + (int)quarter * 64 + ln;
        if (node >= n) break;               // wave-uniform
        int start = basew[ln];
        int npairs = hist[ln] >> 1;         // multiple of 4
        float sdn = s_dst[(size_t)node * 4 + h];

        float acc[8] = {0.f, 0.f, 0.f, 0.f, 0.f, 0.f, 0.f, 0.f};
        float dsum = 0.f;
        int p = grp;
        for (; p + 4 < npairs; p += 8) {
            unsigned c0 = *(const unsigned*)(&csrl[start + 2 * p]);
            unsigned c1 = *(const unsigned*)(&csrl[start + 2 * (p + 4)]);
            int sa0 = c0 & 0xFFFF, sa1 = c0 >> 16;
            int sb0 = c1 & 0xFFFF, sb1 = c1 >> 16;
            uint4 Ua0 = *(const uint4*)(Wxh + ((size_t)sa0 << 7) + l * 8);
            uint4 Ua1 = *(const uint4*)(Wxh + ((size_t)sa1 << 7) + l * 8);
            uint4 Ub0 = *(const uint4*)(Wxh + ((size_t)sb0 << 7) + l * 8);
            uint4 Ub1 = *(const uint4*)(Wxh + ((size_t)sb1 << 7) + l * 8);
            float wa0 = __expf(lrelu(s_src[sa0 * 4 + h] + sdn));
            float wa1 = __expf(lrelu(s_src[sa1 * 4 + h] + sdn));
            float wb0 = __expf(lrelu(s_src[sb0 * 4 + h] + sdn));
            float wb1 = __expf(lrelu(s_src[sb1 * 4 + h] + sdn));
            unsigned wpa = pk2bf(wa0, wa1);
            unsigned wpb = pk2bf(wb0, wb1);
            asm("v_dot2_f32_bf16 %0, %1, %2, %0" : "+v"(dsum) : "v"(wpa), "v"(ONE2));
            asm("v_dot2_f32_bf16 %0, %1, %2, %0" : "+v"(dsum) : "v"(wpb), "v"(ONE2));
            unsigned a0[4] = {Ua0.x, Ua0.y, Ua0.z, Ua0.w};
            unsigned a1[4] = {Ua1.x, Ua1.y, Ua1.z, Ua1.w};
            unsigned b0[4] = {Ub0.x, Ub0.y, Ub0.z, Ub0.w};
            unsigned b1[4] = {Ub1.x, Ub1.y, Ub1.z, Ub1.w};
#pragma unroll
            for (int j = 0; j < 4; ++j) {
                unsigned lo_a = __builtin_amdgcn_perm(a0[j], a1[j], 0x01000504u);
                unsigned hi_a = __builtin_amdgcn_perm(a0[j], a1[j], 0x03020706u);
                unsigned lo_b = __builtin_amdgcn_perm(b0[j], b1[j], 0x01000504u);
                unsigned hi_b = __builtin_amdgcn_perm(b0[j], b1[j], 0x03020706u);
                asm("v_dot2_f32_bf16 %0, %1, %2, %0" : "+v"(acc[2 * j]) : "v"(wpa), "v"(lo_a));
                asm("v_dot2_f32_bf16 %0, %1, %2, %0" : "+v"(acc[2 * j + 1]) : "v"(wpa), "v"(hi_a));
                asm("v_dot2_f32_bf16 %0, %1, %2, %0" : "+v"(acc[2 * j]) : "v"(wpb), "v"(lo_b));
                asm("v_dot2_f32_bf16 %0, %1, %2, %0" : "+v"(acc[2 * j + 1]) : "v"(wpb), "v"(hi_b));
            }
        }
        if (p < npairs) {                   // tail: 4 pairs, wave-uniform condition
            unsigned c0 = *(const unsigned*)(&csrl[start + 2 * p]);
            int sa0 = c0 & 0xFFFF, sa1 = c0 >> 16;
            uint4 Ua0 = *(const uint4*)(Wxh + ((size_t)sa0 << 7) + l * 8);
            uint4 Ua1 = *(const uint4*)(Wxh + ((size_t)sa1 << 7) + l * 8);
            float wa0 = __expf(lrelu(s_src[sa0 * 4 + h] + sdn));
            float wa1 = __expf(lrelu(s_src[sa1 * 4 + h] + sdn));
            unsigned wpa = pk2bf(wa0, wa1);
            asm("v_dot2_f32_bf16 %0, %1, %2, %0" : "+v"(dsum) : "v"(wpa), "v"(ONE2));
            unsigned a0[4] = {Ua0.x, Ua0.y, Ua0.z, Ua0.w};
            unsigned a1[4] = {Ua1.x, Ua1.y, Ua1.z, Ua1.w};
#pragma unroll
            for (int j = 0; j < 4; ++j) {
                unsigned lo_a = __builtin_amdgcn_perm(a0[j], a1[j], 0x01000504u);
                unsigned hi_a = __builtin_amdgcn_perm(a0[j], a1[j], 0x03020706u);
                asm("v_dot2_f32_bf16 %0, %1, %2, %0" : "+v"(acc[2 * j]) : "v"(wpa), "v"(lo_a));
                asm("v_dot2_f32_bf16 %0, %1, %2, %0" : "+v"(acc[2 * j + 1]) : "v"(wpa), "v"(hi_a));
            }
        }
#pragma unroll
        for (int m = 16; m <= 32; m <<= 1) {
#pragma unroll
            for (int j = 0; j < 8; ++j) acc[j] += __shfl_xor(acc[j], m, 64);
            dsum += __shfl_xor(dsum, m, 64);
        }
        if (grp == 0) {
            float inv = 1.f / (dsum + 1e-8f);
            float o[8];
#pragma unroll
            for (int j = 0; j < 8; ++j) {
                float v = acc[j] * inv;
                o[j] = v > 0.f ? v : (__expf(v) - 1.f);
            }
            float4* dp = (float4*)(out + (size_t)node * 128 + l * 8);
            dp[0] = make_float4(o[0], o[1], o[2], o[3]);
            dp[1] = make_float4(o[4], o[5], o[6], o[7]);
        }
    }
}

extern "C" void kernel_launch(void* const* d_in, const int* in_sizes, int n_in,
                              void* d_out, int out_size, void* d_ws, size_t ws_size,
                              hipStream_t stream) {
    const float* x = (const float*)d_in[0];
    const int* ei = (const int*)d_in[1];
    const float* W = (const float*)d_in[2];
    const float* aw = (const float*)d_in[3];
    float* out = (float*)d_out;
    const int n = in_sizes[0] / 128;      // 50000
    const int E = in_sizes[1] / 2;        // 800000

    char* ws = (char*)d_ws;
    size_t off = 0;
    unsigned short* Wxh = (unsigned short*)(ws + off); off += (size_t)(n + 8) * 128 * 2;  // +sentinel row
    float* s_src = (float*)(ws + off);     off += (size_t)(n + 1) * HEADS * 4;            // +sentinel slot
    float* s_dst = (float*)(ws + off);     off += (size_t)n * HEADS * 4;
    int* gcur = (int*)(ws + off);          off += 1024;
    unsigned* gbuf = (unsigned*)(ws + off); off += (size_t)NBKT * CAPB * 4;               // 3.6 MB

    const int ngemm = (n + 127) / 128;                 // 391
    const int npass1 = (E + 4095) / 4096;              // 196

    zero_gcur<<<1, 256, 0, stream>>>(gcur);
    fused_kernel<<<ngemm + npass1, 256, 0, stream>>>(x, W, aw, ei, Wxh, s_src, s_dst,
                                                     gcur, gbuf, n, E, ngemm);
    pass2_accum<<<NBKT * 4, 1024, 0, stream>>>(gcur, gbuf, s_src, s_dst, Wxh, out, n);
}